// Round 1
// baseline (8467.090 us; speedup 1.0000x reference)
//
#include <hip/hip_runtime.h>
#include <cstdint>
#include <cstddef>

#define BB 32
#define HH 512
#define EE 256
#define VV 32000
#define TT 64
#define KDIM 1280   // 2H+E
#define NBLK_V 500  // VV/64

__device__ __forceinline__ float sigf(float x) { return 1.0f / (1.0f + expf(-x)); }

// ---------------------------------------------------------------------------
// Init: featT z-region (k<512) and h-region (k in [768,1280)) = h0[0];
// c buffer 0 = c0[0]. Both ping-pong featT buffers get z and h.
// featT layout: k-major, featT[k*32 + b].
// ---------------------------------------------------------------------------
__global__ __launch_bounds__(256) void k_init(const float* __restrict__ h0,
                                              const float* __restrict__ c0,
                                              float* __restrict__ fA,
                                              float* __restrict__ fB,
                                              float* __restrict__ cA) {
    int idx = blockIdx.x * 256 + threadIdx.x;   // 0..16383
    int kk = idx >> 5;                          // 0..511
    int b  = idx & 31;
    float zv = h0[b * HH + kk];
    fA[kk * BB + b] = zv;
    fB[kk * BB + b] = zv;
    fA[(768 + kk) * BB + b] = zv;
    fB[(768 + kk) * BB + b] = zv;
    cA[b * HH + kk] = c0[b * HH + kk];
}

// ---------------------------------------------------------------------------
// k_gates: per step t.
//  grid = 128 blocks: uc = blockIdx>>2 (16-u chunk of 512), bg = blockIdx&3 (8-b group)
//  4 waves k-split (320 k each); lane l owns gate-row j = uc*16 + (l&15) + 512*(l>>4)
//  Does: argmax finalize (t>0) / y0 read (t==0), gates GEMM (scalar feat loads),
//  LSTM cell, writes h into featT_next h-region, c_next; uc==0 blocks also write
//  the gathered embedding row into featT_next emb-region for k_logits.
// ---------------------------------------------------------------------------
__global__ __launch_bounds__(256) void k_gates(
    int t, const int* __restrict__ y0, const float* __restrict__ emb,
    const float* __restrict__ Wih, const float* __restrict__ Whh,
    const float* __restrict__ bih, const float* __restrict__ bhh,
    const float* __restrict__ fCur, float* __restrict__ fNext,
    const float* __restrict__ cCur, float* __restrict__ cNext,
    const float* __restrict__ apv, const int* __restrict__ api) {
    __shared__ float lds[4 * 2112];   // per-wave 64 rows * 33 floats
    const int tid = threadIdx.x;
    const int l = tid & 63;
    const int wu = __builtin_amdgcn_readfirstlane(tid >> 6);  // wave id, SGPR
    const int uc = blockIdx.x >> 2;
    const int bg = blockIdx.x & 3;
    const int b0 = bg * 8;

    // ---- y for this block's 8 b's (wave-redundant so every wave has SGPR copies)
    int yv0, yv1, yv2, yv3, yv4, yv5, yv6, yv7;
    if (t == 0) {
        yv0 = y0[b0 + 0]; yv1 = y0[b0 + 1]; yv2 = y0[b0 + 2]; yv3 = y0[b0 + 3];
        yv4 = y0[b0 + 4]; yv5 = y0[b0 + 5]; yv6 = y0[b0 + 6]; yv7 = y0[b0 + 7];
    } else {
        int bi = l >> 3;   // 8 lanes per b
        float best = -3.4e38f;
        int bidx = 0x7fffffff;
        for (int e = (l & 7); e < NBLK_V; e += 8) {
            float v = apv[(b0 + bi) * NBLK_V + e];
            int ix = api[(b0 + bi) * NBLK_V + e];
            if (v > best || (v == best && ix < bidx)) { best = v; bidx = ix; }
        }
#pragma unroll
        for (int d = 1; d < 8; d <<= 1) {
            float ov = __shfl_xor(best, d, 8);
            int oi = __shfl_xor(bidx, d, 8);
            if (ov > best || (ov == best && oi < bidx)) { best = ov; bidx = oi; }
        }
        yv0 = __builtin_amdgcn_readlane(bidx, 0);
        yv1 = __builtin_amdgcn_readlane(bidx, 8);
        yv2 = __builtin_amdgcn_readlane(bidx, 16);
        yv3 = __builtin_amdgcn_readlane(bidx, 24);
        yv4 = __builtin_amdgcn_readlane(bidx, 32);
        yv5 = __builtin_amdgcn_readlane(bidx, 40);
        yv6 = __builtin_amdgcn_readlane(bidx, 48);
        yv7 = __builtin_amdgcn_readlane(bidx, 56);
    }
    int yv[8] = {yv0, yv1, yv2, yv3, yv4, yv5, yv6, yv7};

    float acc[8] = {0.f, 0.f, 0.f, 0.f, 0.f, 0.f, 0.f, 0.f};
    float* myW = &lds[wu * 2112];

    for (int ch = 0; ch < 10; ++ch) {
        int kg0 = wu * 320 + ch * 32;
        // stage 64 rows x 32 k into LDS (row stride 33)
#pragma unroll
        for (int i = 0; i < 8; ++i) {
            int f4 = i * 64 + l;
            int r = f4 >> 3;
            int c4 = (f4 & 7) * 4;
            int j = uc * 16 + (r & 15) + 512 * (r >> 4);
            float4 val;
            if (kg0 < 768)
                val = *(const float4*)&Wih[(size_t)j * 768 + kg0 + c4];
            else
                val = *(const float4*)&Whh[(size_t)j * 512 + (kg0 - 768) + c4];
            myW[r * 33 + c4 + 0] = val.x;
            myW[r * 33 + c4 + 1] = val.y;
            myW[r * 33 + c4 + 2] = val.z;
            myW[r * 33 + c4 + 3] = val.w;
        }
        int region = (kg0 < 512) ? 0 : (kg0 < 768 ? 1 : 2);
        if (region == 1) {
            for (int kk = 0; kk < 32; ++kk) {
                float wv = myW[l * 33 + kk];
                int ke = kg0 + kk - 512;
                acc[0] = fmaf(wv, emb[(size_t)yv[0] * EE + ke], acc[0]);
                acc[1] = fmaf(wv, emb[(size_t)yv[1] * EE + ke], acc[1]);
                acc[2] = fmaf(wv, emb[(size_t)yv[2] * EE + ke], acc[2]);
                acc[3] = fmaf(wv, emb[(size_t)yv[3] * EE + ke], acc[3]);
                acc[4] = fmaf(wv, emb[(size_t)yv[4] * EE + ke], acc[4]);
                acc[5] = fmaf(wv, emb[(size_t)yv[5] * EE + ke], acc[5]);
                acc[6] = fmaf(wv, emb[(size_t)yv[6] * EE + ke], acc[6]);
                acc[7] = fmaf(wv, emb[(size_t)yv[7] * EE + ke], acc[7]);
            }
        } else {
            for (int kk = 0; kk < 32; ++kk) {
                float wv = myW[l * 33 + kk];
                const float* fs = &fCur[(kg0 + kk) * BB + b0];
#pragma unroll
                for (int bi = 0; bi < 8; ++bi) acc[bi] = fmaf(wv, fs[bi], acc[bi]);
            }
        }
    }

    // cross-wave reduce via LDS (reuse W staging space; own-region writes safe)
#pragma unroll
    for (int bi = 0; bi < 8; ++bi) myW[l * 33 + bi] = acc[bi];
    __syncthreads();

    if (tid < 128) {
        int ul = tid & 15;
        int bl = tid >> 4;
        float pre[4];
#pragma unroll
        for (int m = 0; m < 4; ++m) {
            int row = ul + 16 * m;
            float s = lds[0 * 2112 + row * 33 + bl] + lds[1 * 2112 + row * 33 + bl] +
                      lds[2 * 2112 + row * 33 + bl] + lds[3 * 2112 + row * 33 + bl];
            int j = uc * 16 + ul + 512 * m;
            pre[m] = s + bih[j] + bhh[j];
        }
        float ig = sigf(pre[0]);
        float fg = sigf(pre[1]);
        float gg = tanhf(pre[2]);
        float og = sigf(pre[3]);
        int u = uc * 16 + ul;
        int b = b0 + bl;
        float cp = cCur[b * HH + u];
        float cn = fg * cp + ig * gg;
        float hn = og * tanhf(cn);
        cNext[b * HH + u] = cn;
        fNext[(768 + u) * BB + b] = hn;
    }
    if (uc == 0) {
        // write gathered embedding rows into featT_next emb-region (for k_logits)
#pragma unroll
        for (int i = 0; i < 8; ++i) {   // i == b-local (idx = tid + 256*i)
            fNext[(512 + tid) * BB + b0 + i] = emb[(size_t)yv[i] * EE + tid];
        }
    }
}

// ---------------------------------------------------------------------------
// k_logits: 500 blocks x 256 thr; block owns 64 vocab rows; 4 waves k-split.
// lane <-> v, 32 fp32 accumulators (one per b), feat read as wave-uniform
// scalar loads from k-major featT. Writes logits (staged t-major or direct)
// and per-block argmax partials.
// ---------------------------------------------------------------------------
__global__ __launch_bounds__(256) void k_logits(
    int t, const float* __restrict__ Wout, const float* __restrict__ bout,
    const float* __restrict__ fNext, float* __restrict__ outbuf, int direct,
    float* __restrict__ apv, int* __restrict__ api) {
    __shared__ float lds[4 * 2112];
    const int tid = threadIdx.x;
    const int l = tid & 63;
    const int wu = __builtin_amdgcn_readfirstlane(tid >> 6);
    const int v0 = blockIdx.x * 64;

    float acc[32];
#pragma unroll
    for (int b = 0; b < 32; ++b) acc[b] = 0.f;
    float* myW = &lds[wu * 2112];

    for (int ch = 0; ch < 10; ++ch) {
        int kg0 = wu * 320 + ch * 32;
#pragma unroll
        for (int i = 0; i < 8; ++i) {
            int f4 = i * 64 + l;
            int r = f4 >> 3;
            int c4 = (f4 & 7) * 4;
            float4 val = *(const float4*)&Wout[(size_t)(v0 + r) * KDIM + kg0 + c4];
            myW[r * 33 + c4 + 0] = val.x;
            myW[r * 33 + c4 + 1] = val.y;
            myW[r * 33 + c4 + 2] = val.z;
            myW[r * 33 + c4 + 3] = val.w;
        }
        for (int kk = 0; kk < 32; ++kk) {
            float wv = myW[l * 33 + kk];
            const float* fs = &fNext[(kg0 + kk) * BB];
#pragma unroll
            for (int b = 0; b < 32; ++b) acc[b] = fmaf(wv, fs[b], acc[b]);
        }
    }

#pragma unroll
    for (int b = 0; b < 32; ++b) myW[l * 33 + b] = acc[b];
    __syncthreads();

#pragma unroll
    for (int i = 0; i < 8; ++i) {
        int b = wu + 4 * i;   // wave-uniform
        float s = lds[0 * 2112 + l * 33 + b] + lds[1 * 2112 + l * 33 + b] +
                  lds[2 * 2112 + l * 33 + b] + lds[3 * 2112 + l * 33 + b] +
                  bout[v0 + l];
        if (!direct)
            outbuf[((size_t)t * BB + b) * VV + v0 + l] = s;
        else
            outbuf[((size_t)b * VV + v0 + l) * TT + t] = s;
        // per-block argmax over 64 v (lowest index wins ties)
        float best = s;
        int bidx = v0 + l;
#pragma unroll
        for (int d = 1; d < 64; d <<= 1) {
            float ov = __shfl_xor(best, d, 64);
            int oi = __shfl_xor(bidx, d, 64);
            if (ov > best || (ov == best && oi < bidx)) { best = ov; bidx = oi; }
        }
        if (l == 0) {
            apv[b * NBLK_V + blockIdx.x] = best;
            api[b * NBLK_V + blockIdx.x] = bidx;
        }
    }
}

// ---------------------------------------------------------------------------
// Final transpose: staged (T,B,V) -> out (B,V,T), fully coalesced both sides.
// ---------------------------------------------------------------------------
__global__ __launch_bounds__(256) void k_trans(const float* __restrict__ staged,
                                               float* __restrict__ out) {
    __shared__ float lds[64 * 65];
    int bx = blockIdx.x;              // 0..15999
    int b = bx / NBLK_V;
    int v0 = (bx % NBLK_V) * 64;
    int tid = threadIdx.x;
    int vl = tid & 63;
    int tq = tid >> 6;
#pragma unroll
    for (int i = 0; i < 16; ++i) {
        int tt = tq * 16 + i;
        lds[tt * 65 + vl] = staged[((size_t)tt * BB + b) * VV + v0 + vl];
    }
    __syncthreads();
    int v2 = tid >> 2;
    int t0 = (tid & 3) * 16;
#pragma unroll
    for (int q = 0; q < 4; ++q) {
        float4 val;
        val.x = lds[(t0 + q * 4 + 0) * 65 + v2];
        val.y = lds[(t0 + q * 4 + 1) * 65 + v2];
        val.z = lds[(t0 + q * 4 + 2) * 65 + v2];
        val.w = lds[(t0 + q * 4 + 3) * 65 + v2];
        *(float4*)&out[((size_t)b * VV + v0 + v2) * TT + t0 + q * 4] = val;
    }
}

// ---------------------------------------------------------------------------
extern "C" void kernel_launch(void* const* d_in, const int* in_sizes, int n_in,
                              void* d_out, int out_size, void* d_ws, size_t ws_size,
                              hipStream_t stream) {
    const int* y0 = (const int*)d_in[0];
    const float* h0 = (const float*)d_in[1];
    const float* c0 = (const float*)d_in[2];
    const float* emb = (const float*)d_in[3];
    const float* Wih = (const float*)d_in[4];
    const float* Whh = (const float*)d_in[5];
    const float* bih = (const float*)d_in[6];
    const float* bhh = (const float*)d_in[7];
    const float* Wout = (const float*)d_in[8];
    const float* bout = (const float*)d_in[9];
    float* out = (float*)d_out;

    const size_t stagedFloats = (size_t)TT * BB * VV;   // 65,536,000
    const size_t smallFloats = 2 * (size_t)KDIM * BB + 2 * (size_t)BB * HH +
                               (size_t)BB * NBLK_V;     // fA+fB + cA+cB + apv
    const size_t smallIntBytes = (size_t)BB * NBLK_V * sizeof(int);
    const size_t needStaged = stagedFloats * 4 + smallFloats * 4 + smallIntBytes + 256;
    int use_staged = (ws_size >= needStaged) ? 1 : 0;

    char* w = (char*)d_ws;
    float* staged = (float*)w;
    size_t off = use_staged ? stagedFloats * 4 : 0;
    float* fA = (float*)(w + off); off += (size_t)KDIM * BB * 4;
    float* fB = (float*)(w + off); off += (size_t)KDIM * BB * 4;
    float* cA = (float*)(w + off); off += (size_t)BB * HH * 4;
    float* cB = (float*)(w + off); off += (size_t)BB * HH * 4;
    float* apv = (float*)(w + off); off += (size_t)BB * NBLK_V * 4;
    int* api = (int*)(w + off);

    k_init<<<64, 256, 0, stream>>>(h0, c0, fA, fB, cA);

    for (int t = 0; t < TT; ++t) {
        const float* fCur = (t & 1) ? fB : fA;
        float* fNext = (t & 1) ? fA : fB;
        const float* cCur = (t & 1) ? cB : cA;
        float* cNext = (t & 1) ? cA : cB;
        k_gates<<<128, 256, 0, stream>>>(t, y0, emb, Wih, Whh, bih, bhh,
                                         fCur, fNext, cCur, cNext, apv, api);
        k_logits<<<NBLK_V, 256, 0, stream>>>(t, Wout, bout, fNext,
                                             use_staged ? staged : out,
                                             use_staged ? 0 : 1, apv, api);
    }
    if (use_staged) k_trans<<<BB * NBLK_V, 256, 0, stream>>>(staged, out);
}

// Round 2
// 7414.515 us; speedup vs baseline: 1.1420x; 1.1420x over previous
//
#include <hip/hip_runtime.h>
#include <cstdint>
#include <cstddef>

#define BB 32
#define HH 512
#define EE 256
#define VV 32000
#define TT 64
#define KDIM 1280    // 2H+E
#define NBLK_V 500   // VV/64
#define WREG 2304    // per-wave LDS region (floats)
#define WTS  68      // transposed W tile stride (floats)

__device__ __forceinline__ float sigf(float x) { return 1.0f / (1.0f + expf(-x)); }

// ---------------------------------------------------------------------------
// k_init: featT z-region (k<512) and h-region (k in [768,1280)) = h0[0] for
// both ping-pong buffers; c buffer A = c0[0]. featT layout: featT[k*32 + b].
// ---------------------------------------------------------------------------
__global__ __launch_bounds__(256) void k_init(const float* __restrict__ h0,
                                              const float* __restrict__ c0,
                                              float* __restrict__ fA,
                                              float* __restrict__ fB,
                                              float* __restrict__ cA) {
    int idx = blockIdx.x * 256 + threadIdx.x;   // 0..16383
    int kk = idx >> 5;                          // 0..511
    int b  = idx & 31;
    float zv = h0[b * HH + kk];
    fA[kk * BB + b] = zv;
    fB[kk * BB + b] = zv;
    fA[(768 + kk) * BB + b] = zv;
    fB[(768 + kk) * BB + b] = zv;
    cA[b * HH + kk] = c0[b * HH + kk];
}

// ---------------------------------------------------------------------------
// k_pre: gzT[j*32+b] = sum_{k<512} Wih[j][k] * z[b][k] + bih[j] + bhh[j].
// grid 32 blocks x 256 thr; block owns 64 j rows; 4 waves k-split (128 each).
// Outer-product: lane owns 4 j x 8 b; W transposed-staged in per-wave LDS.
// ---------------------------------------------------------------------------
__global__ __launch_bounds__(256) void k_pre(const float* __restrict__ Wih,
                                             const float* __restrict__ bih,
                                             const float* __restrict__ bhh,
                                             const float* __restrict__ fz,
                                             float* __restrict__ gzT) {
    __shared__ float lds[4 * WREG];
    const int tid = threadIdx.x;
    const int l = tid & 63;
    const int wu = tid >> 6;
    const int j0 = blockIdx.x * 64;
    const int js = l & 15;   // 4 j rows: r = js*4+i
    const int bg = l >> 4;   // 8 b:     b = bg*8+q
    float* R = &lds[wu * WREG];

    float acc[4][8];
#pragma unroll
    for (int i = 0; i < 4; ++i)
#pragma unroll
        for (int q = 0; q < 8; ++q) acc[i][q] = 0.f;

    for (int ch = 0; ch < 4; ++ch) {
        int kg0 = wu * 128 + ch * 32;
#pragma unroll
        for (int i = 0; i < 8; ++i) {
            int f4 = i * 64 + l;
            int r = f4 >> 3;
            int c4 = (f4 & 7) * 4;
            float4 w = *(const float4*)&Wih[(size_t)(j0 + r) * 768 + kg0 + c4];
            R[(c4 + 0) * WTS + r] = w.x;
            R[(c4 + 1) * WTS + r] = w.y;
            R[(c4 + 2) * WTS + r] = w.z;
            R[(c4 + 3) * WTS + r] = w.w;
        }
#pragma unroll 4
        for (int kk = 0; kk < 32; ++kk) {
            float4 wv = *(const float4*)&R[kk * WTS + js * 4];
            const float* fp = &fz[(kg0 + kk) * BB + bg * 8];
            float4 fa = *(const float4*)fp;
            float4 fb = *(const float4*)(fp + 4);
            float w4[4] = {wv.x, wv.y, wv.z, wv.w};
            float f8[8] = {fa.x, fa.y, fa.z, fa.w, fb.x, fb.y, fb.z, fb.w};
#pragma unroll
            for (int i = 0; i < 4; ++i)
#pragma unroll
                for (int q = 0; q < 8; ++q) acc[i][q] = fmaf(w4[i], f8[q], acc[i][q]);
        }
    }
#pragma unroll
    for (int i = 0; i < 4; ++i) {
        int r = js * 4 + i;
        *(float4*)&R[r * 36 + bg * 8] = make_float4(acc[i][0], acc[i][1], acc[i][2], acc[i][3]);
        *(float4*)&R[r * 36 + bg * 8 + 4] = make_float4(acc[i][4], acc[i][5], acc[i][6], acc[i][7]);
    }
    __syncthreads();
    {
        int j = tid >> 2;
        int bq = (tid & 3) * 8;
        float bias = bih[j0 + j] + bhh[j0 + j];
#pragma unroll
        for (int q = 0; q < 8; ++q) {
            float s = lds[0 * WREG + j * 36 + bq + q] + lds[1 * WREG + j * 36 + bq + q] +
                      lds[2 * WREG + j * 36 + bq + q] + lds[3 * WREG + j * 36 + bq + q];
            gzT[(size_t)(j0 + j) * BB + bq + q] = s + bias;
        }
    }
}

// ---------------------------------------------------------------------------
// k_gates: per step t. grid 128: uc=blk>>2 (16 u of 512), bg4=blk&3 (8 b).
// Finalize argmax (t>0) or read y0; gates = gz + Wih[:,512:]*emb[y] + Whh*h.
// K=768 split 4 ways across waves (192 each, 6 chunks of 32).
// Outer-product: lane owns 4 gate-rows x 2 b; emb read as per-lane gather.
// Epilogue: LSTM cell, write cNext + fNext h-region; uc==0 writes emb region.
// ---------------------------------------------------------------------------
__global__ __launch_bounds__(256) void k_gates(
    int t, const int* __restrict__ y0, const float* __restrict__ emb,
    const float* __restrict__ Wih, const float* __restrict__ Whh,
    const float* __restrict__ gzT,
    const float* __restrict__ fCur, float* __restrict__ fNext,
    const float* __restrict__ cCur, float* __restrict__ cNext,
    const float* __restrict__ apv, const int* __restrict__ api) {
    __shared__ float lds[4 * WREG];
    const int tid = threadIdx.x;
    const int l = tid & 63;
    const int wu = tid >> 6;
    const int uc = blockIdx.x >> 2;
    const int bg4 = blockIdx.x & 3;
    const int b0 = bg4 * 8;
    const int js = l & 15;   // 4 rows: r = js*4+i
    const int bg = l >> 4;   // 2 b:    b = b0 + bg*2 + {0,1}

    // ---- y for this block's 8 b's (SGPR via readlane)
    int yv0, yv1, yv2, yv3, yv4, yv5, yv6, yv7;
    if (t == 0) {
        yv0 = y0[b0 + 0]; yv1 = y0[b0 + 1]; yv2 = y0[b0 + 2]; yv3 = y0[b0 + 3];
        yv4 = y0[b0 + 4]; yv5 = y0[b0 + 5]; yv6 = y0[b0 + 6]; yv7 = y0[b0 + 7];
    } else {
        int bi = l >> 3;   // 8 lanes per b
        float best = -3.4e38f;
        int bidx = 0x7fffffff;
        for (int e = (l & 7); e < NBLK_V; e += 8) {
            float v = apv[(b0 + bi) * NBLK_V + e];
            int ix = api[(b0 + bi) * NBLK_V + e];
            if (v > best || (v == best && ix < bidx)) { best = v; bidx = ix; }
        }
#pragma unroll
        for (int d = 1; d < 8; d <<= 1) {
            float ov = __shfl_xor(best, d, 8);
            int oi = __shfl_xor(bidx, d, 8);
            if (ov > best || (ov == best && oi < bidx)) { best = ov; bidx = oi; }
        }
        yv0 = __builtin_amdgcn_readlane(bidx, 0);
        yv1 = __builtin_amdgcn_readlane(bidx, 8);
        yv2 = __builtin_amdgcn_readlane(bidx, 16);
        yv3 = __builtin_amdgcn_readlane(bidx, 24);
        yv4 = __builtin_amdgcn_readlane(bidx, 32);
        yv5 = __builtin_amdgcn_readlane(bidx, 40);
        yv6 = __builtin_amdgcn_readlane(bidx, 48);
        yv7 = __builtin_amdgcn_readlane(bidx, 56);
    }
    // per-lane emb row bases for the inner gather (bg selects the b-pair)
    int yA = (bg == 0) ? yv0 : (bg == 1) ? yv2 : (bg == 2) ? yv4 : yv6;
    int yB = (bg == 0) ? yv1 : (bg == 1) ? yv3 : (bg == 2) ? yv5 : yv7;
    const float* embA = emb + (size_t)yA * EE;
    const float* embB = emb + (size_t)yB * EE;

    float acc[4][2];
#pragma unroll
    for (int i = 0; i < 4; ++i) { acc[i][0] = 0.f; acc[i][1] = 0.f; }
    float* R = &lds[wu * WREG];

    for (int ch = 0; ch < 6; ++ch) {
        int kg0 = wu * 192 + ch * 32;   // kappa in [0,768); <256: emb, else h
#pragma unroll
        for (int i = 0; i < 8; ++i) {
            int f4 = i * 64 + l;
            int r = f4 >> 3;
            int c4 = (f4 & 7) * 4;
            int j = uc * 16 + (r & 15) + 512 * (r >> 4);
            float4 w;
            if (kg0 < 256)
                w = *(const float4*)&Wih[(size_t)j * 768 + 512 + kg0 + c4];
            else
                w = *(const float4*)&Whh[(size_t)j * 512 + (kg0 - 256) + c4];
            R[(c4 + 0) * WTS + r] = w.x;
            R[(c4 + 1) * WTS + r] = w.y;
            R[(c4 + 2) * WTS + r] = w.z;
            R[(c4 + 3) * WTS + r] = w.w;
        }
        if (kg0 < 256) {
#pragma unroll 4
            for (int kk = 0; kk < 32; ++kk) {
                float4 wv = *(const float4*)&R[kk * WTS + js * 4];
                float f0 = embA[kg0 + kk];
                float f1 = embB[kg0 + kk];
                float w4[4] = {wv.x, wv.y, wv.z, wv.w};
#pragma unroll
                for (int i = 0; i < 4; ++i) {
                    acc[i][0] = fmaf(w4[i], f0, acc[i][0]);
                    acc[i][1] = fmaf(w4[i], f1, acc[i][1]);
                }
            }
        } else {
#pragma unroll 4
            for (int kk = 0; kk < 32; ++kk) {
                float4 wv = *(const float4*)&R[kk * WTS + js * 4];
                float2 hv = *(const float2*)&fCur[(768 + kg0 - 256 + kk) * BB + b0 + bg * 2];
                float w4[4] = {wv.x, wv.y, wv.z, wv.w};
#pragma unroll
                for (int i = 0; i < 4; ++i) {
                    acc[i][0] = fmaf(w4[i], hv.x, acc[i][0]);
                    acc[i][1] = fmaf(w4[i], hv.y, acc[i][1]);
                }
            }
        }
    }
    // partials: [r*8 + bl], bl = bg*2 + {0,1}
#pragma unroll
    for (int i = 0; i < 4; ++i) {
        int r = js * 4 + i;
        *(float2*)&R[r * 8 + bg * 2] = make_float2(acc[i][0], acc[i][1]);
    }
    __syncthreads();

    if (tid < 128) {
        int u = tid & 15;
        int bl = tid >> 4;   // 0..7
        float pre[4];
#pragma unroll
        for (int g = 0; g < 4; ++g) {
            int r = u + 16 * g;
            float s = lds[0 * WREG + r * 8 + bl] + lds[1 * WREG + r * 8 + bl] +
                      lds[2 * WREG + r * 8 + bl] + lds[3 * WREG + r * 8 + bl];
            int j = uc * 16 + u + 512 * g;
            pre[g] = s + gzT[(size_t)j * BB + b0 + bl];
        }
        float ig = sigf(pre[0]);
        float fg = sigf(pre[1]);
        float gg = tanhf(pre[2]);
        float og = sigf(pre[3]);
        int u_g = uc * 16 + u;
        int b = b0 + bl;
        float cp = cCur[b * HH + u_g];
        float cn = fg * cp + ig * gg;
        float hn = og * tanhf(cn);
        cNext[b * HH + u_g] = cn;
        fNext[(768 + u_g) * BB + b] = hn;
    }
    if (uc == 0) {
        int yv[8] = {yv0, yv1, yv2, yv3, yv4, yv5, yv6, yv7};
#pragma unroll
        for (int i = 0; i < 8; ++i)
            fNext[(512 + tid) * BB + b0 + i] = emb[(size_t)yv[i] * EE + tid];
    }
}

// ---------------------------------------------------------------------------
// k_logits: 500 blocks x 256 thr; block owns 64 vocab rows; 4 waves k-split
// (320 each, 10 chunks of 32). Outer-product: lane owns 4 v x 8 b; W
// transposed-staged per-wave in LDS (1 ds_read_b128/kk), feat via 2 float4
// vector loads (per-lane addresses, L1-hot). Epilogue: cross-wave reduce,
// bias, store logits, per-block argmax partials.
// ---------------------------------------------------------------------------
__global__ __launch_bounds__(256) void k_logits(
    int t, const float* __restrict__ Wout, const float* __restrict__ bout,
    const float* __restrict__ feat, float* __restrict__ outbuf, int direct,
    float* __restrict__ apv, int* __restrict__ api) {
    __shared__ float lds[4 * WREG];
    const int tid = threadIdx.x;
    const int l = tid & 63;
    const int wu = tid >> 6;
    const int v0 = blockIdx.x * 64;
    const int vs = l & 15;   // 4 v rows: r = vs*4+i
    const int bg = l >> 4;   // 8 b:     b = bg*8+q
    float* R = &lds[wu * WREG];

    float acc[4][8];
#pragma unroll
    for (int i = 0; i < 4; ++i)
#pragma unroll
        for (int q = 0; q < 8; ++q) acc[i][q] = 0.f;

    for (int ch = 0; ch < 10; ++ch) {
        int kg0 = wu * 320 + ch * 32;
#pragma unroll
        for (int i = 0; i < 8; ++i) {
            int f4 = i * 64 + l;
            int r = f4 >> 3;
            int c4 = (f4 & 7) * 4;
            float4 w = *(const float4*)&Wout[(size_t)(v0 + r) * KDIM + kg0 + c4];
            R[(c4 + 0) * WTS + r] = w.x;
            R[(c4 + 1) * WTS + r] = w.y;
            R[(c4 + 2) * WTS + r] = w.z;
            R[(c4 + 3) * WTS + r] = w.w;
        }
#pragma unroll 4
        for (int kk = 0; kk < 32; ++kk) {
            float4 wv = *(const float4*)&R[kk * WTS + vs * 4];
            const float* fp = &feat[(kg0 + kk) * BB + bg * 8];
            float4 fa = *(const float4*)fp;
            float4 fb = *(const float4*)(fp + 4);
            float w4[4] = {wv.x, wv.y, wv.z, wv.w};
            float f8[8] = {fa.x, fa.y, fa.z, fa.w, fb.x, fb.y, fb.z, fb.w};
#pragma unroll
            for (int i = 0; i < 4; ++i)
#pragma unroll
                for (int q = 0; q < 8; ++q) acc[i][q] = fmaf(w4[i], f8[q], acc[i][q]);
        }
    }
    // partials: [r*36 + b]
#pragma unroll
    for (int i = 0; i < 4; ++i) {
        int r = vs * 4 + i;
        *(float4*)&R[r * 36 + bg * 8] = make_float4(acc[i][0], acc[i][1], acc[i][2], acc[i][3]);
        *(float4*)&R[r * 36 + bg * 8 + 4] = make_float4(acc[i][4], acc[i][5], acc[i][6], acc[i][7]);
    }
    __syncthreads();

    // reduce across waves + bias + store + argmax. thread: b = tid>>3, rg = tid&7
    {
        int b = tid >> 3;
        int rg = tid & 7;
        float best = -3.4e38f;
        int bidx = 0x7fffffff;
#pragma unroll
        for (int i = 0; i < 8; ++i) {
            int r = i * 8 + rg;
            float s = lds[0 * WREG + r * 36 + b] + lds[1 * WREG + r * 36 + b] +
                      lds[2 * WREG + r * 36 + b] + lds[3 * WREG + r * 36 + b] +
                      bout[v0 + r];
            if (!direct)
                outbuf[((size_t)t * BB + b) * VV + v0 + r] = s;
            else
                outbuf[((size_t)b * VV + v0 + r) * TT + t] = s;
            if (s > best) { best = s; bidx = v0 + r; }   // ascending r: keeps lowest
        }
#pragma unroll
        for (int d = 1; d < 8; d <<= 1) {
            float ov = __shfl_xor(best, d, 8);
            int oi = __shfl_xor(bidx, d, 8);
            if (ov > best || (ov == best && oi < bidx)) { best = ov; bidx = oi; }
        }
        if (rg == 0) {
            apv[b * NBLK_V + blockIdx.x] = best;
            api[b * NBLK_V + blockIdx.x] = bidx;
        }
    }
}

// ---------------------------------------------------------------------------
// Final transpose: staged (T,B,V) -> out (B,V,T), coalesced both sides.
// ---------------------------------------------------------------------------
__global__ __launch_bounds__(256) void k_trans(const float* __restrict__ staged,
                                               float* __restrict__ out) {
    __shared__ float lds[64 * 65];
    int bx = blockIdx.x;              // 0..15999
    int b = bx / NBLK_V;
    int v0 = (bx % NBLK_V) * 64;
    int tid = threadIdx.x;
    int vl = tid & 63;
    int tq = tid >> 6;
#pragma unroll
    for (int i = 0; i < 16; ++i) {
        int tt = tq * 16 + i;
        lds[tt * 65 + vl] = staged[((size_t)tt * BB + b) * VV + v0 + vl];
    }
    __syncthreads();
    int v2 = tid >> 2;
    int t0 = (tid & 3) * 16;
#pragma unroll
    for (int q = 0; q < 4; ++q) {
        float4 val;
        val.x = lds[(t0 + q * 4 + 0) * 65 + v2];
        val.y = lds[(t0 + q * 4 + 1) * 65 + v2];
        val.z = lds[(t0 + q * 4 + 2) * 65 + v2];
        val.w = lds[(t0 + q * 4 + 3) * 65 + v2];
        *(float4*)&out[((size_t)b * VV + v0 + v2) * TT + t0 + q * 4] = val;
    }
}

// ---------------------------------------------------------------------------
extern "C" void kernel_launch(void* const* d_in, const int* in_sizes, int n_in,
                              void* d_out, int out_size, void* d_ws, size_t ws_size,
                              hipStream_t stream) {
    const int* y0 = (const int*)d_in[0];
    const float* h0 = (const float*)d_in[1];
    const float* c0 = (const float*)d_in[2];
    const float* emb = (const float*)d_in[3];
    const float* Wih = (const float*)d_in[4];
    const float* Whh = (const float*)d_in[5];
    const float* bih = (const float*)d_in[6];
    const float* bhh = (const float*)d_in[7];
    const float* Wout = (const float*)d_in[8];
    const float* bout = (const float*)d_in[9];
    float* out = (float*)d_out;

    const size_t stagedFloats = (size_t)TT * BB * VV;   // 65,536,000
    const size_t smallBytes = (2 * (size_t)KDIM * BB + 2 * (size_t)BB * HH +
                               4 * HH * BB /*gzT*/ + (size_t)BB * NBLK_V) * 4 +
                              (size_t)BB * NBLK_V * sizeof(int) + 256;
    const size_t needStaged = stagedFloats * 4 + smallBytes;
    int use_staged = (ws_size >= needStaged) ? 1 : 0;

    char* w = (char*)d_ws;
    float* staged = (float*)w;
    size_t off = use_staged ? stagedFloats * 4 : 0;
    float* fA = (float*)(w + off); off += (size_t)KDIM * BB * 4;
    float* fB = (float*)(w + off); off += (size_t)KDIM * BB * 4;
    float* cA = (float*)(w + off); off += (size_t)BB * HH * 4;
    float* cB = (float*)(w + off); off += (size_t)BB * HH * 4;
    float* gzT = (float*)(w + off); off += (size_t)4 * HH * BB * 4;
    float* apv = (float*)(w + off); off += (size_t)BB * NBLK_V * 4;
    int* api = (int*)(w + off);

    k_init<<<64, 256, 0, stream>>>(h0, c0, fA, fB, cA);
    k_pre<<<32, 256, 0, stream>>>(Wih, bih, bhh, fA, gzT);

    for (int t = 0; t < TT; ++t) {
        const float* fCur = (t & 1) ? fB : fA;
        float* fNext = (t & 1) ? fA : fB;
        const float* cCur = (t & 1) ? cB : cA;
        float* cNext = (t & 1) ? cA : cB;
        k_gates<<<128, 256, 0, stream>>>(t, y0, emb, Wih, Whh, gzT,
                                         fCur, fNext, cCur, cNext, apv, api);
        k_logits<<<NBLK_V, 256, 0, stream>>>(t, Wout, bout, fNext,
                                             use_staged ? staged : out,
                                             use_staged ? 0 : 1, apv, api);
    }
    if (use_staged) k_trans<<<BB * NBLK_V, 256, 0, stream>>>(staged, out);
}